// Round 4
// baseline (1292.753 us; speedup 1.0000x reference)
//
#include <hip/hip_runtime.h>
#include <stdint.h>

#define RELS 8
#define F 256
#define KDIM 2304        // 8*256 stacked relations + 256 root/self columns
#define NKT 36           // KDIM / 64 k-tiles
#define TSZ 8192         // shorts per (tile,kt) chunk: 128 rows x 64 cols
#define SCAN_CHUNK 1024  // bins per scan1 block (256 threads x 4)

// A/Wt global layout: tiled + FRAGMENT-MAJOR. chunk(tile,kt) is contiguous
// 16KB holding rows [0,128) x k-units [0,8) (unit = 8 shorts):
//   frag = (row>>6)*8 + ((row>>4)&3)*2 + (unit>>2)      // in [0,16)
//   lane = (unit&3)*16 + (row&15)                       // in [0,64)
//   addr = chunk_base + frag*512 + lane*8 + (k&7)       // shorts
// A wave computing output rows rg*64.. reads fragment (mi,kk) as ONE
// contiguous 1KB global_load_dwordx4 (lane i at +i*16B) straight into the
// mfma_16x16x32 operand layout. No LDS anywhere in the GEMM.

typedef __attribute__((ext_vector_type(8))) short short8;
typedef __attribute__((ext_vector_type(4))) float f32x4;
typedef __attribute__((ext_vector_type(2))) unsigned int uint2v;

__device__ __forceinline__ unsigned short f2bf(float f) {
  union { float f; unsigned int u; } v; v.f = f;
  unsigned int u = v.u;
  if ((u & 0x7f800000u) == 0x7f800000u) return (unsigned short)(u >> 16);
  return (unsigned short)((u + 0x7fffu + ((u >> 16) & 1u)) >> 16);  // RNE
}
__device__ __forceinline__ float bf2f(unsigned short b) {
  union { unsigned int u; float f; } v; v.u = ((unsigned int)b) << 16; return v.f;
}

// ---- x fp32 -> compact bf16 [N,256] (small L3-resident gather source)
__global__ void k_xb(const float* __restrict__ x, unsigned short* __restrict__ xb, int N) {
  int tid = blockIdx.x * blockDim.x + threadIdx.x;
  int n = tid >> 6, q = tid & 63;
  if (n >= N) return;
  const float4 v = *(const float4*)&x[(size_t)n * F + q * 4];
  ushort4 o;
  o.x = f2bf(v.x); o.y = f2bf(v.y); o.z = f2bf(v.z); o.w = f2bf(v.w);
  *(ushort4*)&xb[(size_t)n * F + q * 4] = o;
}

// ---- weight convert+transpose into tiled+fragment-major layout ----
// Wt content: row n (output col), k<2048: W[k][n]; else root[k-2048][n].
__global__ void k_wt(const float* __restrict__ W, const float* __restrict__ root,
                     unsigned short* __restrict__ Wt, int Ncols) {
  int tid = blockIdx.x * blockDim.x + threadIdx.x;
  int total = Ncols * KDIM;
  if (tid >= total) return;
  int n = tid / KDIM, k = tid - n * KDIM;
  float v = (k < 2048) ? W[(size_t)k * Ncols + n] : root[(size_t)(k - 2048) * Ncols + n];
  int tile = n >> 7, row = n & 127;
  int kt = k >> 6, c = k & 63;
  int u = c >> 3, w = c & 7;
  int frag = ((row >> 6) << 3) + (((row >> 4) & 3) << 1) + (u >> 2);
  int dl = ((u & 3) << 4) + (row & 15);
  Wt[(size_t)(tile * NKT + kt) * TSZ + frag * 512 + dl * 8 + w] = f2bf(v);
}

// ---- CSR build ----
__global__ void k_count(const int* __restrict__ ei, const int* __restrict__ et,
                        int* __restrict__ cnt, int E) {
  int e = blockIdx.x * blockDim.x + threadIdx.x;
  if (e >= E) return;
  int bin = ei[E + e] * RELS + et[e];
  atomicAdd(&cnt[bin], 1);
}

__global__ void k_scan1(const int* __restrict__ cnt, int* __restrict__ start,
                        int* __restrict__ bsum, int nb) {
  __shared__ int tsum[256];
  const int t = threadIdx.x;
  const int idx = blockIdx.x * SCAN_CHUNK + t * 4;
  int v[4]; int s = 0;
#pragma unroll
  for (int i = 0; i < 4; i++) { v[i] = (idx + i < nb) ? cnt[idx + i] : 0; s += v[i]; }
  tsum[t] = s;
  __syncthreads();
  for (int d = 1; d < 256; d <<= 1) {
    int a = (t >= d) ? tsum[t - d] : 0;
    __syncthreads();
    tsum[t] += a;
    __syncthreads();
  }
  int ex = (t > 0) ? tsum[t - 1] : 0;
#pragma unroll
  for (int i = 0; i < 4; i++) { if (idx + i < nb) start[idx + i] = ex; ex += v[i]; }
  if (t == 255) bsum[blockIdx.x] = tsum[255];
}

__global__ void k_scan2(int* __restrict__ bsum, int nblocks) {
  __shared__ int sh[1024];
  const int t = threadIdx.x;
  sh[t] = (t < nblocks) ? bsum[t] : 0;
  __syncthreads();
  for (int d = 1; d < 1024; d <<= 1) {
    int a = (t >= d) ? sh[t - d] : 0;
    __syncthreads();
    sh[t] += a;
    __syncthreads();
  }
  if (t < nblocks) bsum[t] = (t > 0) ? sh[t - 1] : 0;
  if (t == 1023) bsum[nblocks] = sh[1023];
}

__global__ void k_scan3(int* __restrict__ start, const int* __restrict__ bsum,
                        int nb, int nblocks) {
  int i = blockIdx.x * blockDim.x + threadIdx.x;
  if (i < nb) start[i] += bsum[i >> 10];
  if (i == 0) start[nb] = bsum[nblocks];
}

__global__ void k_scatter(const int* __restrict__ ei, const int* __restrict__ et,
                          const int* __restrict__ start, int* __restrict__ cur,
                          int* __restrict__ ssrc, int E) {
  int e = blockIdx.x * blockDim.x + threadIdx.x;
  if (e >= E) return;
  int bin = ei[E + e] * RELS + et[e];
  int p = atomicAdd(&cur[bin], 1);
  ssrc[start[bin] + p] = ei[e];
}

// ---- aggregation: one wave per (dst, rel) bin; writes fragment-major A ----
__global__ void k_agg(const unsigned short* __restrict__ src,
                      const int* __restrict__ start, const int* __restrict__ ssrc,
                      unsigned short* __restrict__ A, int nbins) {
  int bin = blockIdx.x * 4 + (threadIdx.x >> 6);
  int lane = threadIdx.x & 63;
  if (bin >= nbins) return;
  int s0 = start[bin], s1 = start[bin + 1];
  int deg = s1 - s0;
  float scale = 1.0f / (float)(deg > 1 ? deg : 1);
  float a0 = 0.f, a1 = 0.f, a2 = 0.f, a3 = 0.f;
  int e = s0;
  for (; e + 1 < s1; e += 2) {           // 2 outstanding gathers per wave
    int sA = ssrc[e], sB = ssrc[e + 1];
    const ushort4 vA = *(const ushort4*)&src[(size_t)sA * F + lane * 4];
    const ushort4 vB = *(const ushort4*)&src[(size_t)sB * F + lane * 4];
    a0 += bf2f(vA.x) + bf2f(vB.x); a1 += bf2f(vA.y) + bf2f(vB.y);
    a2 += bf2f(vA.z) + bf2f(vB.z); a3 += bf2f(vA.w) + bf2f(vB.w);
  }
  if (e < s1) {
    int sA = ssrc[e];
    const ushort4 vA = *(const ushort4*)&src[(size_t)sA * F + lane * 4];
    a0 += bf2f(vA.x); a1 += bf2f(vA.y); a2 += bf2f(vA.z); a3 += bf2f(vA.w);
  }
  int n = bin >> 3, r = bin & 7;
  int tile = n >> 7, row = n & 127;
  int L = lane & 15;
  int kt = r * 4 + (lane >> 4);                 // k-chunk of this lane's 4 shorts
  // feature c = 4*L -> unit u = L>>1, within w = (L&1)*4
  int frag = ((row >> 6) << 3) + (((row >> 4) & 3) << 1) + (L >> 3);
  int dl = (((L >> 1) & 3) << 4) + (row & 15);
  uint2v o;
  o.x = (unsigned)f2bf(a0 * scale) | ((unsigned)f2bf(a1 * scale) << 16);
  o.y = (unsigned)f2bf(a2 * scale) | ((unsigned)f2bf(a3 * scale) << 16);
  __builtin_nontemporal_store(o,
      (uint2v*)&A[(size_t)(tile * NKT + kt) * TSZ + frag * 512 + dl * 8 + (L & 1) * 4]);
}

// ---- copy self features into A's last 256 K-cols (kt 32..35), frag-major ----
__global__ void k_copy_nt(const unsigned short* __restrict__ src, unsigned short* __restrict__ A, int N) {
  int tid = blockIdx.x * blockDim.x + threadIdx.x;
  int n = tid >> 6, q = tid & 63;
  if (n >= N) return;
  const uint2v v = *(const uint2v*)&src[(size_t)n * F + q * 4];
  int tile = n >> 7, row = n & 127;
  int L = q & 15;
  int kt = 32 + (q >> 4);
  int frag = ((row >> 6) << 3) + (((row >> 4) & 3) << 1) + (L >> 3);
  int dl = (((L >> 1) & 3) << 4) + (row & 15);
  __builtin_nontemporal_store(v,
      (uint2v*)&A[(size_t)(tile * NKT + kt) * TSZ + frag * 512 + dl * 8 + (q & 1) * 4]);
}

// ---- 128x128 bf16 MFMA GEMM, LDS-free, fragment-major coalesced loads ----
// Rounds 0-2 (gload_lds, 3 schedules incl. counted-vmcnt) all pinned at
// 2.06-2.11 TB/s beyond-L2 -> LDS-DMA engine caps L2-miss parallelism.
// Round 3 (direct VGPR, scattered 16B granules) dropped to 1.38 TB/s ->
// partial-line requests throttle the miss pipeline. This version: direct
// VGPR loads where EVERY fragment load is one contiguous 1KB dwordx4
// (fragment-major layout above), double-buffered frag sets, no barriers;
// compiler emits per-register counted vmcnt. A/B halves read 2x per block
// from L1/L2 (wave pairs overlap in time -> L1 hits); HBM traffic unchanged.
// Accumulation order is bitwise identical to prior rounds.
template<bool RELU, bool OUTBF16>
__global__ __launch_bounds__(256, 2) void k_gemm(
    const unsigned short* __restrict__ Ag, const unsigned short* __restrict__ Bg,
    const float* __restrict__ bias, void* __restrict__ outp,
    int Nld, int Mreal) {
  const int t = threadIdx.x;
  const int m0 = blockIdx.y * 128;     // y = row tile: the n-tiles sharing an
  const int n0 = blockIdx.x * 128;     // A-panel are linearly adjacent blocks
  const int lane = t & 63, wid = t >> 6;
  const int wm = (wid >> 1) * 64, wn = (wid & 1) * 64;
  const int c15 = lane & 15, quad = lane >> 4;
  // per-wave base (shorts) of its 8 fragments within a chunk
  const int baseA = (wid >> 1) * 4096 + lane * 8;   // frags (rgA*8 + mi*2 + kk)
  const int baseB = (wid & 1) * 4096 + lane * 8;    // frags (rgB*8 + ni*2 + kk)

  f32x4 acc[4][4];
#pragma unroll
  for (int i = 0; i < 4; i++)
#pragma unroll
    for (int j = 0; j < 4; j++) acc[i][j] = (f32x4)0.f;

  const unsigned short* Abase = Ag + (size_t)blockIdx.y * NKT * TSZ + baseA;
  const unsigned short* Bbase = Bg + (size_t)blockIdx.x * NKT * TSZ + baseB;

  short8 a0[4][2], b0[4][2], a1[4][2], b1[4][2];  // two in-flight frag sets

#define LOADF(A_, B_, kt_)                                                   \
  {                                                                          \
    const unsigned short* ap = Abase + (size_t)(kt_) * TSZ;                  \
    const unsigned short* bp = Bbase + (size_t)(kt_) * TSZ;                  \
    _Pragma("unroll")                                                        \
    for (int i = 0; i < 4; i++) {                                            \
      _Pragma("unroll")                                                      \
      for (int kk = 0; kk < 2; kk++) {                                       \
        A_[i][kk] = *(const short8*)(ap + (i * 2 + kk) * 512);               \
        B_[i][kk] = *(const short8*)(bp + (i * 2 + kk) * 512);               \
      }                                                                      \
    }                                                                        \
  }

#define COMPUTE(A_, B_)                                                      \
  {                                                                          \
    _Pragma("unroll")                                                        \
    for (int kk = 0; kk < 2; kk++)                                           \
      _Pragma("unroll")                                                      \
      for (int mi = 0; mi < 4; mi++)                                         \
        _Pragma("unroll")                                                    \
        for (int ni = 0; ni < 4; ni++)                                       \
          acc[mi][ni] = __builtin_amdgcn_mfma_f32_16x16x32_bf16(             \
              A_[mi][kk], B_[ni][kk], acc[mi][ni], 0, 0, 0);                 \
  }

  LOADF(a0, b0, 0);
  LOADF(a1, b1, 1);
#pragma unroll 1
  for (int kt = 0; kt < NKT - 2; kt += 2) {
    COMPUTE(a0, b0);          // waits only until set-0 landed (set-1 in flight)
    LOADF(a0, b0, kt + 2);    // refill set 0 (16 more 1KB loads in flight)
    COMPUTE(a1, b1);
    LOADF(a1, b1, kt + 3);
  }
  COMPUTE(a0, b0);            // chunks NKT-2, NKT-1
  COMPUTE(a1, b1);
#undef LOADF
#undef COMPUTE

#pragma unroll
  for (int mi = 0; mi < 4; mi++) {
#pragma unroll
    for (int ni = 0; ni < 4; ni++) {
      int n = n0 + wn + ni * 16 + c15;
      float bv = bias[n];
#pragma unroll
      for (int r = 0; r < 4; r++) {
        int m = m0 + wm + mi * 16 + quad * 4 + r;
        if (m < Mreal) {
          float v = acc[mi][ni][r] + bv;
          if (RELU) v = v > 0.f ? v : 0.f;
          if (OUTBF16) ((unsigned short*)outp)[(size_t)m * Nld + n] = f2bf(v);
          else         ((float*)outp)[(size_t)m * Nld + n] = v;
        }
      }
    }
  }
}

extern "C" void kernel_launch(void* const* d_in, const int* in_sizes, int n_in,
                              void* d_out, int out_size, void* d_ws, size_t ws_size,
                              hipStream_t stream) {
  const float* x     = (const float*)d_in[0];
  const int*   ei    = (const int*)d_in[1];   // [2, E]: src row then dst row
  const int*   et    = (const int*)d_in[2];   // [E]
  const float* W1    = (const float*)d_in[3]; // [2048,256]
  const float* root1 = (const float*)d_in[4]; // [256,256]
  const float* b1    = (const float*)d_in[5];
  const float* W2    = (const float*)d_in[6]; // [2048,128]
  const float* root2 = (const float*)d_in[7]; // [256,128]
  const float* b2    = (const float*)d_in[8];

  const int N = in_sizes[0] / F;              // 50000
  const int E = in_sizes[2];                  // 800000
  const int nbins = N * RELS;                 // 400000
  const int Mpad = ((N + 127) / 128) * 128;   // 50048
  const int ntiles = Mpad / 128;              // 391
  const int nsb = (nbins + SCAN_CHUNK - 1) / SCAN_CHUNK;

  char* base = (char*)d_ws;
  size_t off = 0;
  auto alloc = [&](size_t bytes) {
    void* r = base + off;
    off = (off + bytes + 511) & ~(size_t)511;
    return r;
  };
  unsigned short* Wt1  = (unsigned short*)alloc((size_t)2 * NKT * TSZ * 2);  // 256 cols
  unsigned short* Wt2  = (unsigned short*)alloc((size_t)1 * NKT * TSZ * 2);  // 128 cols
  int*            cnt  = (int*)alloc((size_t)nbins * 4);
  int*            strt = (int*)alloc((size_t)(nbins + 1) * 4);
  int*            bsum = (int*)alloc((size_t)(nsb + 1) * 4);
  int*            ssrc = (int*)alloc((size_t)E * 4);
  // xh: single buffer aliased across lifetimes — layer-1 gather source
  // (bf16 x), then overwritten by GEMM1 as h, then layer-2 gather source.
  unsigned short* xh   = (unsigned short*)alloc((size_t)Mpad * F * 2);
  unsigned short* A    = (unsigned short*)alloc((size_t)ntiles * NKT * TSZ * 2);
  (void)ws_size; (void)n_in; (void)out_size;

  hipMemsetAsync(cnt, 0, (size_t)nbins * 4, stream);
  k_xb<<<(N * 64 + 255) / 256, 256, 0, stream>>>(x, xh, N);
  k_wt<<<(256 * KDIM + 255) / 256, 256, 0, stream>>>(W1, root1, Wt1, 256);
  k_wt<<<(128 * KDIM + 255) / 256, 256, 0, stream>>>(W2, root2, Wt2, 128);
  k_count<<<(E + 255) / 256, 256, 0, stream>>>(ei, et, cnt, E);
  k_scan1<<<nsb, 256, 0, stream>>>(cnt, strt, bsum, nbins);
  k_scan2<<<1, 1024, 0, stream>>>(bsum, nsb);
  k_scan3<<<(nbins + 255) / 256, 256, 0, stream>>>(strt, bsum, nbins, nsb);
  hipMemsetAsync(cnt, 0, (size_t)nbins * 4, stream);  // reuse as cursor
  k_scatter<<<(E + 255) / 256, 256, 0, stream>>>(ei, et, strt, cnt, ssrc, E);

  // Layer 1: gather from compact xh (bf16 x); A written nontemporal (tiled).
  // GEMM1 then overwrites xh with h (xh's x-copy is dead by that point).
  k_agg<<<(nbins + 3) / 4, 256, 0, stream>>>(xh, strt, ssrc, A, nbins);
  k_copy_nt<<<(N * 64 + 255) / 256, 256, 0, stream>>>(xh, A, N);
  k_gemm<true, true><<<dim3(2, ntiles), 256, 0, stream>>>(A, Wt1, b1, xh, 256, N);

  // Layer 2: gather from compact xh (now h).
  k_agg<<<(nbins + 3) / 4, 256, 0, stream>>>(xh, strt, ssrc, A, nbins);
  k_copy_nt<<<(N * 64 + 255) / 256, 256, 0, stream>>>(xh, A, N);
  k_gemm<false, false><<<dim3(1, ntiles), 256, 0, stream>>>(A, Wt2, b2, d_out, 128, N);
}

// Round 5
// 670.955 us; speedup vs baseline: 1.9267x; 1.9267x over previous
//
#include <hip/hip_runtime.h>
#include <stdint.h>

#define RELS 8
#define F 256
#define KDIM 2304        // 8*256 stacked relations + 256 root/self columns
#define NKT 36           // KDIM / 64 k-tiles
#define TSZ 8192         // shorts per (tile,kt) chunk: 128 rows x 64 cols
#define SCAN_CHUNK 1024  // bins per scan1 block (256 threads x 4)

// Wt global layout: tiled + FRAGMENT-MAJOR (round-4 verified). chunk(tile,kt)
// is contiguous 16KB holding rows [0,128) x k-units [0,8) (unit = 8 shorts):
//   frag = (row>>6)*8 + ((row>>4)&3)*2 + (unit>>2)      // in [0,16)
//   lane = (unit&3)*16 + (row&15)                       // in [0,64)
//   addr = chunk_base + frag*512 + lane*8 + (k&7)       // shorts
// A wave reads fragment (mi,kk) as ONE contiguous 1KB dwordx4 straight into
// the mfma_16x16x32 operand layout. The SAME layout is used for the per-
// relation A-slice in LDS inside k_fused (scatter writes are free in LDS).

typedef __attribute__((ext_vector_type(8))) short short8;
typedef __attribute__((ext_vector_type(4))) float f32x4;
typedef __attribute__((ext_vector_type(2))) unsigned int uint2v;

__device__ __forceinline__ unsigned short f2bf(float f) {
  union { float f; unsigned int u; } v; v.f = f;
  unsigned int u = v.u;
  if ((u & 0x7f800000u) == 0x7f800000u) return (unsigned short)(u >> 16);
  return (unsigned short)((u + 0x7fffu + ((u >> 16) & 1u)) >> 16);  // RNE
}
__device__ __forceinline__ float bf2f(unsigned short b) {
  union { unsigned int u; float f; } v; v.u = ((unsigned int)b) << 16; return v.f;
}

// ---- x fp32 -> compact bf16 [N,256] (small L3-resident gather source)
__global__ void k_xb(const float* __restrict__ x, unsigned short* __restrict__ xb, int N) {
  int tid = blockIdx.x * blockDim.x + threadIdx.x;
  int n = tid >> 6, q = tid & 63;
  if (n >= N) return;
  const float4 v = *(const float4*)&x[(size_t)n * F + q * 4];
  ushort4 o;
  o.x = f2bf(v.x); o.y = f2bf(v.y); o.z = f2bf(v.z); o.w = f2bf(v.w);
  *(ushort4*)&xb[(size_t)n * F + q * 4] = o;
}

// ---- weight convert+transpose into tiled+fragment-major layout ----
// Wt content: row n (output col), k<2048: W[k][n]; else root[k-2048][n].
__global__ void k_wt(const float* __restrict__ W, const float* __restrict__ root,
                     unsigned short* __restrict__ Wt, int Ncols) {
  int tid = blockIdx.x * blockDim.x + threadIdx.x;
  int total = Ncols * KDIM;
  if (tid >= total) return;
  int n = tid / KDIM, k = tid - n * KDIM;
  float v = (k < 2048) ? W[(size_t)k * Ncols + n] : root[(size_t)(k - 2048) * Ncols + n];
  int tile = n >> 7, row = n & 127;
  int kt = k >> 6, c = k & 63;
  int u = c >> 3, w = c & 7;
  int frag = ((row >> 6) << 3) + (((row >> 4) & 3) << 1) + (u >> 2);
  int dl = ((u & 3) << 4) + (row & 15);
  Wt[(size_t)(tile * NKT + kt) * TSZ + frag * 512 + dl * 8 + w] = f2bf(v);
}

// ---- CSR build ----
__global__ void k_count(const int* __restrict__ ei, const int* __restrict__ et,
                        int* __restrict__ cnt, int E) {
  int e = blockIdx.x * blockDim.x + threadIdx.x;
  if (e >= E) return;
  int bin = ei[E + e] * RELS + et[e];
  atomicAdd(&cnt[bin], 1);
}

__global__ void k_scan1(const int* __restrict__ cnt, int* __restrict__ start,
                        int* __restrict__ bsum, int nb) {
  __shared__ int tsum[256];
  const int t = threadIdx.x;
  const int idx = blockIdx.x * SCAN_CHUNK + t * 4;
  int v[4]; int s = 0;
#pragma unroll
  for (int i = 0; i < 4; i++) { v[i] = (idx + i < nb) ? cnt[idx + i] : 0; s += v[i]; }
  tsum[t] = s;
  __syncthreads();
  for (int d = 1; d < 256; d <<= 1) {
    int a = (t >= d) ? tsum[t - d] : 0;
    __syncthreads();
    tsum[t] += a;
    __syncthreads();
  }
  int ex = (t > 0) ? tsum[t - 1] : 0;
#pragma unroll
  for (int i = 0; i < 4; i++) { if (idx + i < nb) start[idx + i] = ex; ex += v[i]; }
  if (t == 255) bsum[blockIdx.x] = tsum[255];
}

__global__ void k_scan2(int* __restrict__ bsum, int nblocks) {
  __shared__ int sh[1024];
  const int t = threadIdx.x;
  sh[t] = (t < nblocks) ? bsum[t] : 0;
  __syncthreads();
  for (int d = 1; d < 1024; d <<= 1) {
    int a = (t >= d) ? sh[t - d] : 0;
    __syncthreads();
    sh[t] += a;
    __syncthreads();
  }
  if (t < nblocks) bsum[t] = (t > 0) ? sh[t - 1] : 0;
  if (t == 1023) bsum[nblocks] = sh[1023];
}

__global__ void k_scan3(int* __restrict__ start, const int* __restrict__ bsum,
                        int nb, int nblocks) {
  int i = blockIdx.x * blockDim.x + threadIdx.x;
  if (i < nb) start[i] += bsum[i >> 10];
  if (i == 0) start[nb] = bsum[nblocks];
}

__global__ void k_scatter(const int* __restrict__ ei, const int* __restrict__ et,
                          const int* __restrict__ start, int* __restrict__ cur,
                          int* __restrict__ ssrc, int E) {
  int e = blockIdx.x * blockDim.x + threadIdx.x;
  if (e >= E) return;
  int bin = ei[E + e] * RELS + et[e];
  int p = atomicAdd(&cur[bin], 1);
  ssrc[start[bin] + p] = ei[e];
}

// ---- FUSED per-tile kernel: aggregate -> LDS slice -> MFMA, per relation ----
// Rounds 0-4 showed the A materialization path (agg -> 225MB HBM write ->
// 225MB HBM read -> GEMM) is pinned at ~2.1 TB/s by per-CU miss concurrency,
// independent of staging scheme (gload_lds x3 schedules, direct VGPR x2
// layouts). This kernel never materializes A: per 128-row tile and per
// relation slice r, 8 waves aggregate their 16 rows' (dst,rel) bins from the
// L3-resident feature buffer into a 64KB fragment-major LDS slice, then MFMA
// it against the frag-major Wt chunks (kt = r*4..r*4+3). Accumulator lives
// across all 9 slices -> identical k-order/rounding as the unfused version.
// Saves ~450MB of HBM round-trip per layer; gather stays in L3.
template<int NI, bool RELU, bool OUTBF16>
__global__ __launch_bounds__(512, 4) void k_fused(
    const unsigned short* __restrict__ src, const unsigned short* __restrict__ Wt,
    const int* __restrict__ start, const int* __restrict__ ssrc,
    const float* __restrict__ bias, void* __restrict__ outp, int Nreal) {
  __shared__ unsigned short slice[4 * 8192];   // 64 KB: [chunk c][frag][dlane][8]
  const int t = threadIdx.x;
  const int lane = t & 63, wid = t >> 6;       // 8 waves
  const int m0 = blockIdx.x * 128;
  const int c15 = lane & 15, quad = lane >> 4;
  const int wm = (wid >> 2) * 64;              // 2 m-halves
  const int wn = (wid & 3) * (NI * 16);        // 4 n-quarters (NI*16 cols each)
  // gather-lane constants: lane covers feats [lane*4, lane*4+4) of the slice
  const int gc = lane >> 4;                    // k-chunk within slice
  const int gL = lane & 15;
  const int gFragLo = (gL >> 3);               // frag bit from unit
  const int gDlHi = ((gL >> 1) & 3) << 4;
  const int gW = (gL & 1) * 4;

  f32x4 acc[4][NI];
#pragma unroll
  for (int i = 0; i < 4; i++)
#pragma unroll
    for (int j = 0; j < NI; j++) acc[i][j] = (f32x4)0.f;

  const unsigned short* Bt = Wt + (size_t)(wn >> 7) * NKT * TSZ + lane * 8;

  for (int r = 0; r < 9; r++) {
    // ---- phase 1: build fragment-major A-slice for relation r in LDS ----
    if (r < 8) {
#pragma unroll 1
      for (int bi = 0; bi < 16; bi++) {
        int row = (wid << 4) + bi;
        int n = m0 + row;
        float a0 = 0.f, a1 = 0.f, a2 = 0.f, a3 = 0.f, scale = 1.f;
        if (n < Nreal) {
          int bin = n * RELS + r;
          int s0 = start[bin], s1 = start[bin + 1];
          int deg = s1 - s0;
          scale = 1.0f / (float)(deg > 1 ? deg : 1);
          int e = s0;
          for (; e + 1 < s1; e += 2) {       // 2 outstanding gathers
            int sA = ssrc[e], sB = ssrc[e + 1];
            const ushort4 vA = *(const ushort4*)&src[(size_t)sA * F + lane * 4];
            const ushort4 vB = *(const ushort4*)&src[(size_t)sB * F + lane * 4];
            a0 += bf2f(vA.x) + bf2f(vB.x); a1 += bf2f(vA.y) + bf2f(vB.y);
            a2 += bf2f(vA.z) + bf2f(vB.z); a3 += bf2f(vA.w) + bf2f(vB.w);
          }
          if (e < s1) {
            int sA = ssrc[e];
            const ushort4 vA = *(const ushort4*)&src[(size_t)sA * F + lane * 4];
            a0 += bf2f(vA.x); a1 += bf2f(vA.y); a2 += bf2f(vA.z); a3 += bf2f(vA.w);
          }
        }
        int frag = ((row >> 6) << 3) | (((row >> 4) & 3) << 1) | gFragLo;
        int dl = gDlHi | (row & 15);
        uint2v o;
        o.x = (unsigned)f2bf(a0 * scale) | ((unsigned)f2bf(a1 * scale) << 16);
        o.y = (unsigned)f2bf(a2 * scale) | ((unsigned)f2bf(a3 * scale) << 16);
        *(uint2v*)&slice[gc * 8192 + frag * 512 + dl * 8 + gW] = o;
      }
    } else {
      // self slice: raw copy of this tile's own features
#pragma unroll 1
      for (int bi = 0; bi < 16; bi++) {
        int row = (wid << 4) + bi;
        int n = m0 + row;                      // src has Mpad rows (padded)
        const uint2v v = *(const uint2v*)&src[(size_t)n * F + lane * 4];
        int frag = ((row >> 6) << 3) | (((row >> 4) & 3) << 1) | gFragLo;
        int dl = gDlHi | (row & 15);
        *(uint2v*)&slice[gc * 8192 + frag * 512 + dl * 8 + gW] = v;
      }
    }
    __syncthreads();
    // ---- phase 2: MFMA slice x Wt chunks kt = r*4 .. r*4+3 ----
#pragma unroll
    for (int c = 0; c < 4; c++) {
      const unsigned short* bc = Bt + (size_t)(r * 4 + c) * TSZ;
#pragma unroll
      for (int kk = 0; kk < 2; kk++) {
        short8 bfr[NI], afr[4];
#pragma unroll
        for (int ni = 0; ni < NI; ni++) {
          int rB = (wn & 127) + ni * 16;
          int fB = ((rB >> 6) << 3) + (((rB >> 4) & 3) << 1) + kk;
          bfr[ni] = *(const short8*)(bc + fB * 512);
        }
#pragma unroll
        for (int mi = 0; mi < 4; mi++) {
          int fA = ((wm >> 6) << 3) + (mi << 1) + kk;
          afr[mi] = *(const short8*)&slice[c * 8192 + fA * 512 + lane * 8];
        }
#pragma unroll
        for (int mi = 0; mi < 4; mi++)
#pragma unroll
          for (int ni = 0; ni < NI; ni++)
            acc[mi][ni] = __builtin_amdgcn_mfma_f32_16x16x32_bf16(
                afr[mi], bfr[ni], acc[mi][ni], 0, 0, 0);
      }
    }
    __syncthreads();   // before overwriting the slice with the next relation
  }

  // ---- epilogue: bias (+relu) and store; output width = NI*64 ----
  const int Nld = NI * 64;
#pragma unroll
  for (int mi = 0; mi < 4; mi++) {
#pragma unroll
    for (int ni = 0; ni < NI; ni++) {
      int n = wn + ni * 16 + c15;
      float bv = bias[n];
#pragma unroll
      for (int rr = 0; rr < 4; rr++) {
        int m = m0 + wm + mi * 16 + quad * 4 + rr;
        if (m < Nreal) {
          float v = acc[mi][ni][rr] + bv;
          if (RELU) v = v > 0.f ? v : 0.f;
          if (OUTBF16) ((unsigned short*)outp)[(size_t)m * Nld + n] = f2bf(v);
          else         ((float*)outp)[(size_t)m * Nld + n] = v;
        }
      }
    }
  }
}

extern "C" void kernel_launch(void* const* d_in, const int* in_sizes, int n_in,
                              void* d_out, int out_size, void* d_ws, size_t ws_size,
                              hipStream_t stream) {
  const float* x     = (const float*)d_in[0];
  const int*   ei    = (const int*)d_in[1];   // [2, E]: src row then dst row
  const int*   et    = (const int*)d_in[2];   // [E]
  const float* W1    = (const float*)d_in[3]; // [2048,256]
  const float* root1 = (const float*)d_in[4]; // [256,256]
  const float* b1    = (const float*)d_in[5];
  const float* W2    = (const float*)d_in[6]; // [2048,128]
  const float* root2 = (const float*)d_in[7]; // [256,128]
  const float* b2    = (const float*)d_in[8];

  const int N = in_sizes[0] / F;              // 50000
  const int E = in_sizes[2];                  // 800000
  const int nbins = N * RELS;                 // 400000
  const int Mpad = ((N + 127) / 128) * 128;   // 50048
  const int ntiles = Mpad / 128;              // 391
  const int nsb = (nbins + SCAN_CHUNK - 1) / SCAN_CHUNK;

  char* base = (char*)d_ws;
  size_t off = 0;
  auto alloc = [&](size_t bytes) {
    void* r = base + off;
    off = (off + bytes + 511) & ~(size_t)511;
    return r;
  };
  unsigned short* Wt1  = (unsigned short*)alloc((size_t)2 * NKT * TSZ * 2);  // 256 cols
  unsigned short* Wt2  = (unsigned short*)alloc((size_t)1 * NKT * TSZ * 2);  // 128 cols
  int*            cnt  = (int*)alloc((size_t)nbins * 4);
  int*            strt = (int*)alloc((size_t)(nbins + 1) * 4);
  int*            bsum = (int*)alloc((size_t)(nsb + 1) * 4);
  int*            ssrc = (int*)alloc((size_t)E * 4);
  unsigned short* xb   = (unsigned short*)alloc((size_t)Mpad * F * 2);  // bf16 x
  unsigned short* h    = (unsigned short*)alloc((size_t)Mpad * F * 2);  // bf16 h (layer-1 out)
  (void)ws_size; (void)n_in; (void)out_size;

  hipMemsetAsync(cnt, 0, (size_t)nbins * 4, stream);
  k_xb<<<(N * 64 + 255) / 256, 256, 0, stream>>>(x, xb, N);
  k_wt<<<(256 * KDIM + 255) / 256, 256, 0, stream>>>(W1, root1, Wt1, 256);
  k_wt<<<(128 * KDIM + 255) / 256, 256, 0, stream>>>(W2, root2, Wt2, 128);
  k_count<<<(E + 255) / 256, 256, 0, stream>>>(ei, et, cnt, E);
  k_scan1<<<nsb, 256, 0, stream>>>(cnt, strt, bsum, nbins);
  k_scan2<<<1, 1024, 0, stream>>>(bsum, nsb);
  k_scan3<<<(nbins + 255) / 256, 256, 0, stream>>>(strt, bsum, nbins, nsb);
  hipMemsetAsync(cnt, 0, (size_t)nbins * 4, stream);  // reuse as cursor
  k_scatter<<<(E + 255) / 256, 256, 0, stream>>>(ei, et, strt, cnt, ssrc, E);

  // Layer 1: gather x (bf16, L3-resident) -> h. No A materialization.
  k_fused<4, true, true><<<ntiles, 512, 0, stream>>>(xb, Wt1, strt, ssrc, b1, h, N);
  // Layer 2: gather h -> output (fp32).
  k_fused<2, false, false><<<ntiles, 512, 0, stream>>>(h, Wt2, strt, ssrc, b2, d_out, N);
}